// Round 6
// baseline (89.738 us; speedup 1.0000x reference)
//
#include <hip/hip_runtime.h>
#include <math.h>

#define MARGIN 0.2f
#define NEG_WEIGHT 0.5f

constexpr int Bc = 64, Nc = 16, Lc = 1024, DH = 64, Ac = 8;
constexpr int NSAMP = Bc * Ac;            // 512
constexpr int CHUNKS = 16;                // chunks per sample
constexpr int RPC = Lc / CHUNKS;          // 64 rows per chunk
constexpr int WPB = 4;                    // waves (tasks) per block
constexpr int GRID = NSAMP * CHUNKS / WPB;  // 2048 blocks

__device__ __forceinline__ float pdist(float x2, float y2, float d2) {
    x2 = fminf(x2, 0.999999f);
    y2 = fminf(y2, 0.999999f);
    float num = 2.0f * d2;
    float den = (1.0f - x2) * (1.0f - y2);
    float ratio = num * __builtin_amdgcn_rcpf(fmaxf(den, 1e-15f));
    float z = 1.0f + fmaxf(ratio, 1.0f + 1e-7f);
    // z >= 1 + 1e-7: acosh via log
    return __logf(z + __builtin_sqrtf(z * z - 1.0f));
}

// Fused: 2048 blocks x 256 threads. Wave w of block blk handles task
// t = blk*4 + w -> (s = t>>4, c = t&15): rows [c*64, c*64+64) of sample s.
// Chunks entirely <= lt are skipped (hinge contribution provably 0).
// Last block to finish performs the final reduction (threadfence + atomic).
__global__ __launch_bounds__(256) void fused_kernel(
    const float* __restrict__ h_curr,
    const float* __restrict__ demo_h,
    const int*   __restrict__ align_idx,
    const int*   __restrict__ lookahead_p,
    float* __restrict__ wneg,     // [NSAMP*CHUNKS*2] hinge,cnt
    float* __restrict__ wpos,     // [NSAMP*2] d_pos,validflag
    unsigned int* __restrict__ counter,
    float* __restrict__ out)
{
    const int tid  = threadIdx.x;
    const int wave = tid >> 6;
    const int lane = tid & 63;
    const int task = blockIdx.x * WPB + wave;
    const int s    = task >> 4;
    const int c    = task & 15;
    const int b    = s >> 3;
    const int quad = lane & 3;
    const int rg   = lane >> 2;

    const int n0 = align_idx[s * 2 + 0];
    const int l0 = align_idx[s * 2 + 1];
    const int lt = l0 + lookahead_p[0];
    const bool valid = (lt >= 0) && (lt < Lc);
    const bool dead  = (c * RPC + (RPC - 1)) <= lt;   // all rows <= lt
    const bool need_dpos = valid && ((c == 0) || !dead);
    const bool do_hinge  = valid && !dead;

    float d_pos = 0.0f;
    float hinge_acc = 0.0f, cnt_acc = 0.0f;

    if (need_dpos) {   // wave-uniform
        const int lt_c = min(max(lt, 0), Lc - 1);
        const float* __restrict__ xrow = h_curr + (size_t)b * DH + quad * 16;
        const float* __restrict__ seq  = demo_h + (((size_t)b * Nc + (size_t)n0) * Lc) * DH;

        float4 xv[4];
        #pragma unroll
        for (int j = 0; j < 4; ++j)
            xv[j] = *reinterpret_cast<const float4*>(xrow + j * 4);

        float x2 = 0.0f;
        #pragma unroll
        for (int j = 0; j < 4; ++j) {
            x2 = fmaf(xv[j].x, xv[j].x, x2);
            x2 = fmaf(xv[j].y, xv[j].y, x2);
            x2 = fmaf(xv[j].z, xv[j].z, x2);
            x2 = fmaf(xv[j].w, xv[j].w, x2);
        }
        x2 += __shfl_xor(x2, 1, 64);
        x2 += __shfl_xor(x2, 2, 64);

        {
            const float* rowp = seq + (size_t)(min(max(lt, 0), Lc - 1)) * DH + quad * 16;
            float d2 = 0.0f, y2 = 0.0f;
            #pragma unroll
            for (int j = 0; j < 4; ++j) {
                float4 yv = *reinterpret_cast<const float4*>(rowp + j * 4);
                float dx = xv[j].x - yv.x, dy = xv[j].y - yv.y;
                float dz = xv[j].z - yv.z, dw = xv[j].w - yv.w;
                d2 = fmaf(dx, dx, d2); d2 = fmaf(dy, dy, d2);
                d2 = fmaf(dz, dz, d2); d2 = fmaf(dw, dw, d2);
                y2 = fmaf(yv.x, yv.x, y2); y2 = fmaf(yv.y, yv.y, y2);
                y2 = fmaf(yv.z, yv.z, y2); y2 = fmaf(yv.w, yv.w, y2);
            }
            d2 += __shfl_xor(d2, 1, 64); d2 += __shfl_xor(d2, 2, 64);
            y2 += __shfl_xor(y2, 1, 64); y2 += __shfl_xor(y2, 2, 64);
            d_pos = pdist(x2, y2, d2);
        }

        if (do_hinge) {   // wave-uniform
            const float* __restrict__ seqh = seq;
            #pragma unroll
            for (int it = 0; it < 4; ++it) {
                const int row = c * RPC + it * 16 + rg;
                const float* rowp = seqh + (size_t)row * DH + quad * 16;
                float d2 = 0.0f, y2 = 0.0f;
                #pragma unroll
                for (int j = 0; j < 4; ++j) {
                    float4 yv = *reinterpret_cast<const float4*>(rowp + j * 4);
                    float dx = xv[j].x - yv.x, dy = xv[j].y - yv.y;
                    float dz = xv[j].z - yv.z, dw = xv[j].w - yv.w;
                    d2 = fmaf(dx, dx, d2); d2 = fmaf(dy, dy, d2);
                    d2 = fmaf(dz, dz, d2); d2 = fmaf(dw, dw, d2);
                    y2 = fmaf(yv.x, yv.x, y2); y2 = fmaf(yv.y, yv.y, y2);
                    y2 = fmaf(yv.z, yv.z, y2); y2 = fmaf(yv.w, yv.w, y2);
                }
                d2 += __shfl_xor(d2, 1, 64); d2 += __shfl_xor(d2, 2, 64);
                y2 += __shfl_xor(y2, 1, 64); y2 += __shfl_xor(y2, 2, 64);
                float dneg = pdist(x2, y2, d2);
                if (row > lt) {
                    hinge_acc += fmaxf(MARGIN - dneg + d_pos, 0.0f);
                    cnt_acc   += 1.0f;
                }
            }
            #pragma unroll
            for (int m = 4; m < 64; m <<= 1) {
                hinge_acc += __shfl_xor(hinge_acc, m, 64);
                cnt_acc   += __shfl_xor(cnt_acc,   m, 64);
            }
        }
    }

    if (lane == 0) {
        wneg[(size_t)(s * CHUNKS + c) * 2 + 0] = hinge_acc;
        wneg[(size_t)(s * CHUNKS + c) * 2 + 1] = cnt_acc;
        if (c == 0) {
            wpos[(size_t)s * 2 + 0] = valid ? d_pos : 0.0f;
            wpos[(size_t)s * 2 + 1] = valid ? 1.0f : 0.0f;
        }
    }

    // ---- last-block final reduction ----
    __shared__ int isLast;
    __syncthreads();
    if (tid == 0) {
        __threadfence();
        unsigned int old = atomicAdd(counter, 1u);
        isLast = (old == (unsigned int)(GRID - 1)) ? 1 : 0;
    }
    __syncthreads();
    if (isLast) {
        __threadfence();   // acquire: make all blocks' ws writes visible
        float pn = 0.0f, pv = 0.0f, nn = 0.0f, nc = 0.0f;
        for (int ss = tid; ss < NSAMP; ss += 256) {
            float h = 0.0f, ct = 0.0f;
            #pragma unroll
            for (int cc = 0; cc < CHUNKS; ++cc) {
                h  += wneg[(size_t)(ss * CHUNKS + cc) * 2 + 0];
                ct += wneg[(size_t)(ss * CHUNKS + cc) * 2 + 1];
            }
            float per_sample = h / fmaxf(ct, 1.0f);
            float has_neg = (ct > 0.0f) ? 1.0f : 0.0f;
            nn += per_sample * has_neg;
            nc += has_neg;
            pn += wpos[(size_t)ss * 2 + 0];
            pv += wpos[(size_t)ss * 2 + 1];
        }
        __shared__ float4 sh[256];
        sh[tid] = make_float4(pn, pv, nn, nc);
        __syncthreads();
        for (int off = 128; off > 0; off >>= 1) {
            if (tid < off) {
                sh[tid].x += sh[tid + off].x;
                sh[tid].y += sh[tid + off].y;
                sh[tid].z += sh[tid + off].z;
                sh[tid].w += sh[tid + off].w;
            }
            __syncthreads();
        }
        if (tid == 0) {
            float pos_term = sh[0].x / fmaxf(sh[0].y, 1.0f);
            float neg_term = sh[0].z / fmaxf(sh[0].w, 1.0f);
            out[0] = pos_term + NEG_WEIGHT * neg_term;
        }
    }
}

extern "C" void kernel_launch(void* const* d_in, const int* in_sizes, int n_in,
                              void* d_out, int out_size, void* d_ws, size_t ws_size,
                              hipStream_t stream) {
    const float* h_curr    = (const float*)d_in[0];
    const float* demo_h    = (const float*)d_in[1];
    const int*   align_idx = (const int*)d_in[2];
    const int*   lookahead = (const int*)d_in[3];
    float* out = (float*)d_out;

    // ws layout: [0..255] counter (uses 4B, 256B reserved for alignment),
    // then wneg (NSAMP*CHUNKS*2 floats), then wpos (NSAMP*2 floats)
    unsigned int* counter = (unsigned int*)d_ws;
    float* wneg = (float*)((char*)d_ws + 256);
    float* wpos = wneg + (size_t)NSAMP * CHUNKS * 2;

    hipMemsetAsync(counter, 0, sizeof(unsigned int), stream);
    fused_kernel<<<GRID, 256, 0, stream>>>(
        h_curr, demo_h, align_idx, lookahead, wneg, wpos, counter, out);
}

// Round 7
// 24.507 us; speedup vs baseline: 3.6617x; 3.6617x over previous
//
#include <hip/hip_runtime.h>
#include <math.h>

#define MARGIN 0.2f
#define NEG_WEIGHT 0.5f

constexpr int Bc = 64, Nc = 16, Lc = 1024, DH = 64, Ac = 8;
constexpr int NSAMP = Bc * Ac;            // 512
constexpr int CHUNKS = 16;                // chunks per sample
constexpr int ROWS_PER_CHUNK = Lc / CHUNKS;  // 64 rows
constexpr int WPB = 4;                    // waves (tasks) per block
constexpr int GRID = NSAMP * CHUNKS / WPB;   // 2048 blocks

__device__ __forceinline__ float fast_acosh(float z) {
    // z >= 1 + 1e-7 guaranteed by clamp
    return __logf(z + __builtin_sqrtf(z * z - 1.0f));
}

__device__ __forceinline__ float pdist(float x2, float y2, float d2) {
    x2 = fminf(x2, 0.999999f);
    y2 = fminf(y2, 0.999999f);
    float num = 2.0f * d2;
    float den = (1.0f - x2) * (1.0f - y2);
    float ratio = num * __builtin_amdgcn_rcpf(fmaxf(den, 1e-15f));
    float z = 1.0f + fmaxf(ratio, 1.0f + 1e-7f);
    return fast_acosh(z);
}

// R5 structure, ONE change: 4 independent wave-tasks per 256-thread block
// (same task decomposition, no __syncthreads — waves exit independently).
// task = blockIdx*4 + waveid -> (s = task>>4, c = task&15)
// lane layout: quad = lane&3 owns dims [quad*16, quad*16+16); rg = lane>>2 owns a row
__global__ __launch_bounds__(256) void sample_kernel(
    const float* __restrict__ h_curr,
    const float* __restrict__ demo_h,
    const int*   __restrict__ align_idx,
    const int*   __restrict__ lookahead_p,
    float* __restrict__ ws)
{
    const int tid  = threadIdx.x;
    const int task = blockIdx.x * WPB + (tid >> 6);
    const int s    = task >> 4;        // sample 0..511
    const int c    = task & 15;        // chunk  0..15
    const int b    = s >> 3;           // s / Ac
    const int lane = tid & 63;
    const int quad = lane & 3;
    const int rg   = lane >> 2;        // 0..15

    const int n0 = align_idx[s * 2 + 0];
    const int l0 = align_idx[s * 2 + 1];
    const int lk = lookahead_p[0];
    const int lt = l0 + lk;
    const bool valid = (lt >= 0) && (lt < Lc);

    if (!valid) {
        if (lane == 0) {
            float* wneg = ws + (size_t)(s * CHUNKS + c) * 2;
            wneg[0] = 0.0f; wneg[1] = 0.0f;
            if (c == 0) {
                float* wpos = ws + (size_t)NSAMP * CHUNKS * 2 + (size_t)s * 2;
                wpos[0] = 0.0f; wpos[1] = 0.0f;
            }
        }
        return;
    }

    // chunks whose rows are all <= lt contribute nothing — skip the 16 KB read
    const bool dead = (c * ROWS_PER_CHUNK + (ROWS_PER_CHUNK - 1)) <= lt;
    if (dead && c != 0) {
        if (lane == 0) {
            float* wneg = ws + (size_t)(s * CHUNKS + c) * 2;
            wneg[0] = 0.0f; wneg[1] = 0.0f;
        }
        return;
    }

    const int lt_c = min(max(lt, 0), Lc - 1);

    const float* __restrict__ xrow = h_curr + (size_t)b * DH + quad * 16;
    const float* __restrict__ seq  = demo_h + (((size_t)b * Nc + (size_t)n0) * Lc) * DH;

    // x fragment: 16 dims per lane
    float4 xv[4];
    #pragma unroll
    for (int j = 0; j < 4; ++j)
        xv[j] = *reinterpret_cast<const float4*>(xrow + j * 4);

    float x2 = 0.0f;
    #pragma unroll
    for (int j = 0; j < 4; ++j) {
        x2 = fmaf(xv[j].x, xv[j].x, x2);
        x2 = fmaf(xv[j].y, xv[j].y, x2);
        x2 = fmaf(xv[j].z, xv[j].z, x2);
        x2 = fmaf(xv[j].w, xv[j].w, x2);
    }
    x2 += __shfl_xor(x2, 1, 64);
    x2 += __shfl_xor(x2, 2, 64);   // x2 valid in all lanes of each quad-group

    // d_pos from row lt_c
    float d_pos;
    {
        const float* rowp = seq + (size_t)lt_c * DH + quad * 16;
        float d2 = 0.0f, y2 = 0.0f;
        #pragma unroll
        for (int j = 0; j < 4; ++j) {
            float4 yv = *reinterpret_cast<const float4*>(rowp + j * 4);
            float dx = xv[j].x - yv.x, dy = xv[j].y - yv.y;
            float dz = xv[j].z - yv.z, dw = xv[j].w - yv.w;
            d2 = fmaf(dx, dx, d2); d2 = fmaf(dy, dy, d2);
            d2 = fmaf(dz, dz, d2); d2 = fmaf(dw, dw, d2);
            y2 = fmaf(yv.x, yv.x, y2); y2 = fmaf(yv.y, yv.y, y2);
            y2 = fmaf(yv.z, yv.z, y2); y2 = fmaf(yv.w, yv.w, y2);
        }
        d2 += __shfl_xor(d2, 1, 64); d2 += __shfl_xor(d2, 2, 64);
        y2 += __shfl_xor(y2, 1, 64); y2 += __shfl_xor(y2, 2, 64);
        d_pos = pdist(x2, y2, d2);
    }

    if (dead) {   // only possible for c == 0: write d_pos, zero hinge, exit
        if (lane == 0) {
            float* wneg = ws + (size_t)(s * CHUNKS + c) * 2;
            wneg[0] = 0.0f; wneg[1] = 0.0f;
            float* wpos = ws + (size_t)NSAMP * CHUNKS * 2 + (size_t)s * 2;
            wpos[0] = d_pos; wpos[1] = 1.0f;
        }
        return;
    }

    // negatives: 64 rows of this chunk, 16 rows per pass (one per row-group)
    float hinge_acc = 0.0f, cnt_acc = 0.0f;
    #pragma unroll
    for (int it = 0; it < 4; ++it) {
        const int row = c * ROWS_PER_CHUNK + it * 16 + rg;
        const float* rowp = seq + (size_t)row * DH + quad * 16;
        float d2 = 0.0f, y2 = 0.0f;
        #pragma unroll
        for (int j = 0; j < 4; ++j) {
            float4 yv = *reinterpret_cast<const float4*>(rowp + j * 4);
            float dx = xv[j].x - yv.x, dy = xv[j].y - yv.y;
            float dz = xv[j].z - yv.z, dw = xv[j].w - yv.w;
            d2 = fmaf(dx, dx, d2); d2 = fmaf(dy, dy, d2);
            d2 = fmaf(dz, dz, d2); d2 = fmaf(dw, dw, d2);
            y2 = fmaf(yv.x, yv.x, y2); y2 = fmaf(yv.y, yv.y, y2);
            y2 = fmaf(yv.z, yv.z, y2); y2 = fmaf(yv.w, yv.w, y2);
        }
        d2 += __shfl_xor(d2, 1, 64); d2 += __shfl_xor(d2, 2, 64);
        y2 += __shfl_xor(y2, 1, 64); y2 += __shfl_xor(y2, 2, 64);
        float dneg = pdist(x2, y2, d2);
        if (row > lt) {
            hinge_acc += fmaxf(MARGIN - dneg + d_pos, 0.0f);
            cnt_acc   += 1.0f;
        }
    }

    // values are uniform within each quad; sum across the 16 row-groups only
    #pragma unroll
    for (int m = 4; m < 64; m <<= 1) {
        hinge_acc += __shfl_xor(hinge_acc, m, 64);
        cnt_acc   += __shfl_xor(cnt_acc,   m, 64);
    }

    if (lane == 0) {
        float* wneg = ws + (size_t)(s * CHUNKS + c) * 2;
        wneg[0] = hinge_acc;
        wneg[1] = cnt_acc;
        if (c == 0) {
            float* wpos = ws + (size_t)NSAMP * CHUNKS * 2 + (size_t)s * 2;
            wpos[0] = d_pos; wpos[1] = 1.0f;
        }
    }
}

__global__ __launch_bounds__(256) void reduce_kernel(
    const float* __restrict__ ws, float* __restrict__ out)
{
    const int tid = threadIdx.x;
    float pn = 0.0f, pv = 0.0f, nn = 0.0f, nc = 0.0f;
    for (int s = tid; s < NSAMP; s += 256) {
        float h = 0.0f, ct = 0.0f;
        #pragma unroll
        for (int c = 0; c < CHUNKS; ++c) {
            h  += ws[(size_t)(s * CHUNKS + c) * 2 + 0];
            ct += ws[(size_t)(s * CHUNKS + c) * 2 + 1];
        }
        float per_sample = h / fmaxf(ct, 1.0f);
        float has_neg = (ct > 0.0f) ? 1.0f : 0.0f;
        nn += per_sample * has_neg;
        nc += has_neg;
        pn += ws[(size_t)NSAMP * CHUNKS * 2 + (size_t)s * 2 + 0];
        pv += ws[(size_t)NSAMP * CHUNKS * 2 + (size_t)s * 2 + 1];
    }
    __shared__ float4 sh[256];
    sh[tid] = make_float4(pn, pv, nn, nc);
    __syncthreads();
    for (int off = 128; off > 0; off >>= 1) {
        if (tid < off) {
            sh[tid].x += sh[tid + off].x;
            sh[tid].y += sh[tid + off].y;
            sh[tid].z += sh[tid + off].z;
            sh[tid].w += sh[tid + off].w;
        }
        __syncthreads();
    }
    if (tid == 0) {
        float pos_term = sh[0].x / fmaxf(sh[0].y, 1.0f);
        float neg_term = sh[0].z / fmaxf(sh[0].w, 1.0f);
        out[0] = pos_term + NEG_WEIGHT * neg_term;
    }
}

extern "C" void kernel_launch(void* const* d_in, const int* in_sizes, int n_in,
                              void* d_out, int out_size, void* d_ws, size_t ws_size,
                              hipStream_t stream) {
    const float* h_curr    = (const float*)d_in[0];
    const float* demo_h    = (const float*)d_in[1];
    const int*   align_idx = (const int*)d_in[2];
    const int*   lookahead = (const int*)d_in[3];
    float* out = (float*)d_out;
    float* ws  = (float*)d_ws;

    sample_kernel<<<GRID, 256, 0, stream>>>(h_curr, demo_h, align_idx, lookahead, ws);
    reduce_kernel<<<1, 256, 0, stream>>>(ws, out);
}